// Round 5
// baseline (239.129 us; speedup 1.0000x reference)
//
#include <hip/hip_runtime.h>
#include <hip/hip_bf16.h>
#include <math.h>

#define NSTEP 100
#define BATCH 16384
#define MB 16            // samples per wave == MFMA dim 16
#define NBLK (BATCH/MB)  // 1024 blocks x 1 wave, zero in-loop barriers
#define NT 64

#define C_ALPHA 0.05f
#define C_SIGMA 0.2f
#define C_THETA 0.3f
#define C_DT    0.01f
#define C_LOWER 1e-6f
#define C_PEN   100.0f
#define LOG2E   1.4426950408889634f
#define TSCALE  (2.0f * LOG2E)      // tanh(z) = 1 - 2/(exp2(TSCALE*z)+1) (table build only)
#define CRT ( 0.015f * C_DT * LOG2E)
#define CRW ( 0.1f * LOG2E)
#define CPT (-0.095f * C_DT * LOG2E)
#define CPW (-0.3f * LOG2E)

// table coordinate: u = TSC*z + TOFF, 1024 segments over z in [-8, 8]
#define TSC   64.0f
#define TOFF  512.0f
#define TMAX  1023.999f
#define AXD   (1.0f + C_ALPHA * C_DT)
#define SIGTHDT (C_SIGMA * C_THETA * C_DT)

typedef __attribute__((ext_vector_type(8))) short bf16x8;
typedef __attribute__((ext_vector_type(4))) float f32x4;
typedef __attribute__((ext_vector_type(4), aligned(4))) float f32x4a;

__device__ __forceinline__ float tanh_pre(float zs) {  // zs = TSCALE*z (trans; init only)
    float e = __builtin_amdgcn_exp2f(zs);
    return 1.0f - 2.0f * __builtin_amdgcn_rcpf(e + 1.0f);
}
__device__ __forceinline__ unsigned f2bf_u(float f) {  // RNE
    unsigned u = __float_as_uint(f);
    return (u + 0x7FFFu + ((u >> 16) & 1u)) >> 16;
}
__device__ __forceinline__ unsigned pack_bf16(float a, float b) {
    union { __hip_bfloat162 h; unsigned u; } cv;
    cv.h = __float22bfloat162_rn(make_float2(a, b));   // v_cvt_pk_bf16_f32
    return cv.u;
}
// sum across each 16-lane row via DPP row_ror butterfly; all lanes get the sum
__device__ __forceinline__ float dpp_row_sum16(float v) {
    int t;
    t = __builtin_amdgcn_update_dpp(0, __float_as_int(v), 0x128, 0xF, 0xF, true);
    v += __int_as_float(t);
    t = __builtin_amdgcn_update_dpp(0, __float_as_int(v), 0x124, 0xF, 0xF, true);
    v += __int_as_float(t);
    t = __builtin_amdgcn_update_dpp(0, __float_as_int(v), 0x122, 0xF, 0xF, true);
    v += __int_as_float(t);
    t = __builtin_amdgcn_update_dpp(0, __float_as_int(v), 0x121, 0xF, 0xF, true);
    v += __int_as_float(t);
    return v;
}

__global__ __launch_bounds__(NT, 1) void fused_kernel(
        const float* __restrict__ dw, const float* __restrict__ X0,
        const float* __restrict__ R0,
        const float* __restrict__ pW1, const float* __restrict__ pb1,
        const float* __restrict__ pW2, const float* __restrict__ pb2,
        const float* __restrict__ pW3, const float* __restrict__ pb3,
        const float* __restrict__ qW1, const float* __restrict__ qb1,
        const float* __restrict__ qW2, const float* __restrict__ qb2,
        const float* __restrict__ qW3, const float* __restrict__ qb3,
        float* __restrict__ ws, float* __restrict__ out) {
    __shared__ __align__(16) unsigned short sW2T[64 * 72];  // bf16 W2^T [n][k] * TSC
    __shared__ __align__(16) float sdw[MB * NSTEP];
    __shared__ __align__(16) float2 sTab[1024];             // PWL tanh: {t, dt}

    const int tid = threadIdx.x;
    const int lane = tid;                  // one wave per block
    const int b0 = blockIdx.x * MB;
    const int l15 = lane & 15, quad = lane >> 4;

    // ---- stage dw (coalesced float4), W2^T (bf16, *TSC), tanh PWL table ----
    {
        const float4* g = (const float4*)(dw + (size_t)b0 * NSTEP);
        float4* s = (float4*)sdw;
        for (int u = tid; u < MB * NSTEP / 4; u += NT) s[u] = g[u];
    }
    for (int u4 = tid; u4 < 1024; u4 += NT) {
        float4 w = ((const float4*)qW2)[u4];
        int base = u4 * 4;
        int k = base >> 6, n = base & 63;      // qW2[k*64+n] = W2[k][n]
        sW2T[(n + 0) * 72 + k] = (unsigned short)f2bf_u(w.x * TSC);
        sW2T[(n + 1) * 72 + k] = (unsigned short)f2bf_u(w.y * TSC);
        sW2T[(n + 2) * 72 + k] = (unsigned short)f2bf_u(w.z * TSC);
        sW2T[(n + 3) * 72 + k] = (unsigned short)f2bf_u(w.w * TSC);
    }
    for (int u = tid; u < 1024; u += NT) {     // build PWL table (one-time trans)
        float z0 = (float)u * (1.0f / TSC) - 8.0f;
        float t0 = tanh_pre(TSCALE * z0);
        float t1 = tanh_pre(TSCALE * (z0 + 1.0f / TSC));
        sTab[u] = make_float2(t0, t1 - t0);
    }
    __syncthreads();   // only barrier in the kernel (init staging)

    // PWL tanh eval: u is already the table coordinate (weights pre-scaled)
    auto tab = [&](float u) -> float {
        u = fmaxf(u, 0.0f);
        u = fminf(u, TMAX);
        int idx = (int)u;                      // trunc == floor (u >= 0)
        float f = u - (float)idx;
        float2 e = sTab[idx];
        return fmaf(f, e.y, e.x);
    };

    // resident W2^T fragments: ALL 4 n-tiles x 2 k-steps (MFMA A operand)
    bf16x8 Bf[4][2];
    #pragma unroll
    for (int nt = 0; nt < 4; nt++) {
        const unsigned short* rp = &sW2T[(nt * 16 + l15) * 72 + quad * 8];
        Bf[nt][0] = *(const bf16x8*)rp;
        Bf[nt][1] = *(const bf16x8*)(rp + 32);
    }
    // layer-1 consts, pre-scaled by TSC with +TOFF folded into bias:
    // k0 = quad*8+j (kstep0), k1 = 32+quad*8+j (kstep1)
    float tco[16], w1xs[16], w1rs[16], b1s[16];
    {
        const int kq = quad * 8;
        #pragma unroll
        for (int j = 0; j < 8; j++) {
            tco[j]      = qW1[kq + j]        * (2.0f * C_DT * TSC);
            tco[8 + j]  = qW1[32 + kq + j]   * (2.0f * C_DT * TSC);
            w1xs[j]     = qW1[64 + kq + j]   * TSC;
            w1xs[8 + j] = qW1[96 + kq + j]   * TSC;
            w1rs[j]     = qW1[128 + kq + j]  * TSC;
            w1rs[8 + j] = qW1[160 + kq + j]  * TSC;
            b1s[j]      = qb1[kq + j]        * TSC + TOFF;
            b1s[8 + j]  = qb1[32 + kq + j]   * TSC + TOFF;
        }
    }
    // acc[nt][r] = table-coord of h2pre[n = nt*16 + quad*4 + r][sample l15]
    f32x4 b2a[4];
    float w3c[4][4];
    #pragma unroll
    for (int nt = 0; nt < 4; nt++) {
        #pragma unroll
        for (int r = 0; r < 4; r++) {
            b2a[nt][r] = qb2[nt * 16 + quad * 4 + r] * TSC + TOFF;
            w3c[nt][r] = qW3[nt * 16 + quad * 4 + r];
        }
    }
    const float b3 = qb3[0];
    const float X0v = X0[0], R0s = R0[0];

    // ---- p-net: p0, dp0 (one-time; trans ok here) ----
    float p0, dp0;
    {
        float pre = fmaf(pW1[64 + lane], X0v, fmaf(pW1[128 + lane], R0s, pb1[lane]));
        float h1 = tanh_pre(TSCALE * pre);
        float d1 = (1.0f - h1 * h1) * pW1[64 + lane];
        float a0 = pb2[lane], a1 = 0.f, a2 = 0.f, a3 = 0.f;
        float e0 = 0.f, e1 = 0.f, e2 = 0.f, e3 = 0.f;
        for (int i2 = 0; i2 < 64; i2 += 4) {
            float w0 = pW2[(i2 + 0) * 64 + lane];
            float w1 = pW2[(i2 + 1) * 64 + lane];
            float w2 = pW2[(i2 + 2) * 64 + lane];
            float w3 = pW2[(i2 + 3) * 64 + lane];
            a0 = fmaf(__shfl(h1, i2 + 0), w0, a0); e0 = fmaf(__shfl(d1, i2 + 0), w0, e0);
            a1 = fmaf(__shfl(h1, i2 + 1), w1, a1); e1 = fmaf(__shfl(d1, i2 + 1), w1, e1);
            a2 = fmaf(__shfl(h1, i2 + 2), w2, a2); e2 = fmaf(__shfl(d1, i2 + 2), w2, e2);
            a3 = fmaf(__shfl(h1, i2 + 3), w3, a3); e3 = fmaf(__shfl(d1, i2 + 3), w3, e3);
        }
        float pre2 = (a0 + a1) + (a2 + a3);
        float dpre2 = (e0 + e1) + (e2 + e3);
        float h2 = tanh_pre(TSCALE * pre2);
        float d2 = (1.0f - h2 * h2) * dpre2;
        float c1 = h2 * pW3[lane], c2 = d2 * pW3[lane];
        #pragma unroll
        for (int o = 1; o < 64; o <<= 1) {
            c1 += __shfl_xor(c1, o);
            c2 += __shfl_xor(c2, o);
        }
        p0 = c1 + pb3[0]; dp0 = c2;
    }
    const float mdp0 = -dp0;

    // ---- single-wave q-net: table tanh, no barriers, pi on ALL lanes ----
    auto qnet = [&](float fi, float xv, float rv) -> float {
        union { bf16x8 v; unsigned u[4]; } A0u, A1u;
        #pragma unroll
        for (int p = 0; p < 4; p++) {
            const int i0 = 2 * p, i1 = 2 * p + 1;
            float z0 = fmaf(w1rs[i0], rv, fmaf(w1xs[i0], xv, fmaf(tco[i0], fi, b1s[i0])));
            float z1 = fmaf(w1rs[i1], rv, fmaf(w1xs[i1], xv, fmaf(tco[i1], fi, b1s[i1])));
            A0u.u[p] = pack_bf16(tab(z0), tab(z1));
            float z2 = fmaf(w1rs[8 + i0], rv, fmaf(w1xs[8 + i0], xv, fmaf(tco[8 + i0], fi, b1s[8 + i0])));
            float z3 = fmaf(w1rs[8 + i1], rv, fmaf(w1xs[8 + i1], xv, fmaf(tco[8 + i1], fi, b1s[8 + i1])));
            A1u.u[p] = pack_bf16(tab(z2), tab(z3));
        }
        // swapped operands: D[row = n-within-tile][col = SAMPLE = lane&15]
        float ps0 = 0.f, ps1 = 0.f, ps2 = 0.f, ps3 = 0.f;
        #pragma unroll
        for (int nt = 0; nt < 4; nt++) {
            f32x4 a = b2a[nt];
            a = __builtin_amdgcn_mfma_f32_16x16x32_bf16(Bf[nt][0], A0u.v, a, 0, 0, 0);
            a = __builtin_amdgcn_mfma_f32_16x16x32_bf16(Bf[nt][1], A1u.v, a, 0, 0, 0);
            ps0 = fmaf(tab(a[0]), w3c[nt][0], ps0);
            ps1 = fmaf(tab(a[1]), w3c[nt][1], ps1);
            ps2 = fmaf(tab(a[2]), w3c[nt][2], ps2);
            ps3 = fmaf(tab(a[3]), w3c[nt][3], ps3);
        }
        float ps = (ps0 + ps1) + (ps2 + ps3);   // 16 of 64 n-terms (this quad's rows)
        ps += __shfl_xor(ps, 16);               // cross-quad: all 64 n-terms
        ps += __shfl_xor(ps, 32);
        return ps + b3;
    };

    // ---- t=0 row + initial pi ----
    float x = X0v, minx = X0v;
    float R = R0s, pm = p0;                    // multiplicative carries
    float pi = qnet(0.0f, X0v, R0s);
    {
        size_t base = (size_t)(b0 + l15) * 5;
        if (quad == 0) {
            f32x4a o = {X0v, R0s, pi, -p0};
            *(f32x4a*)(out + base) = o;
        } else if (quad == 1) {
            out[base + 4] = mdp0;
        }
    }

    float dw_next = sdw[l15 * NSTEP];
    #pragma unroll 1
    for (int i = 0; i < NSTEP - 1; i++) {
        const float fi = (float)(i + 1);
        float dwv = dw_next;
        dw_next = sdw[l15 * NSTEP + i + 1];
        // off-chain multiplicative R / pm updates (only trans in the loop)
        R  *= __builtin_amdgcn_exp2f(fmaf(CRW, dwv, CRT));
        pm *= __builtin_amdgcn_exp2f(fmaf(CPW, dwv, CPT));
        float sp = fmaf(dwv, C_SIGMA, SIGTHDT);
        x = fmaf(x, AXD, pi * sp);
        minx = fminf(minx, x);
        float pin = qnet(fi, x, R);
        size_t base = ((size_t)(i + 1) * BATCH + b0 + l15) * 5;
        if (quad == 0) {
            f32x4a o = {x, R, pin, -pm};
            *(f32x4a*)(out + base) = o;
        } else if (quad == 1) {
            out[base + 4] = mdp0;
        }
        pi = pin;
    }

    // ---- final step (pi not updated) + losses ----
    {
        float dwv = dw_next;
        R  *= __builtin_amdgcn_exp2f(fmaf(CRW, dwv, CRT));
        pm *= __builtin_amdgcn_exp2f(fmaf(CPW, dwv, CPT));
        float sp = fmaf(dwv, C_SIGMA, SIGTHDT);
        x = fmaf(x, AXD, pi * sp);
        minx = fminf(minx, x);
        float Rf = R, pf = pm;
        size_t base = ((size_t)NSTEP * BATCH + b0 + l15) * 5;
        if (quad == 0) {
            f32x4a o = {x, Rf, pi, -pf};
            *(f32x4a*)(out + base) = o;
        } else if (quad == 1) {
            out[base + 4] = mdp0;
        }
        // losses: values replicated across quads; each 16-lane row sums 16 samples
        float xc = fmaxf(x, C_LOWER);
        float ux = Rf * rsqrtf(xc);           // R * xc^(gamma-1), gamma=0.5
        float uval = 2.0f * Rf * sqrtf(xc);   // R * xc^gamma / gamma
        float d = fmaxf(C_LOWER - minx, 0.0f);
        float pen = C_PEN * d * d;
        float t1 = pf + ux;
        float v1 = dpp_row_sum16(t1 * t1 + pen);
        float v2 = dpp_row_sum16(-uval + pen);
        if (lane == 0) {
            atomicAdd(&ws[3], v1);
            atomicAdd(&ws[4], v2);
            __threadfence();
            int old = atomicAdd((int*)(ws + 5), 1);
            if (old == NBLK - 1) {   // last block finalizes losses
                float lp = atomicAdd(&ws[3], 0.0f) * (1.0f / (float)BATCH);
                float lq = atomicAdd(&ws[4], 0.0f) * (1.0f / (float)BATCH);
                out[(size_t)(NSTEP + 1) * BATCH * 5] = lp;
                out[(size_t)(NSTEP + 1) * BATCH * 5 + 1] = lp + lq;
            }
        }
    }
}

extern "C" void kernel_launch(void* const* d_in, const int* in_sizes, int n_in,
                              void* d_out, int out_size, void* d_ws, size_t ws_size,
                              hipStream_t stream) {
    const float* dw  = (const float*)d_in[0];
    const float* X0  = (const float*)d_in[1];
    const float* R0  = (const float*)d_in[2];
    const float* pW1 = (const float*)d_in[3];
    const float* pb1 = (const float*)d_in[4];
    const float* pW2 = (const float*)d_in[5];
    const float* pb2 = (const float*)d_in[6];
    const float* pW3 = (const float*)d_in[7];
    const float* pb3 = (const float*)d_in[8];
    const float* qW1 = (const float*)d_in[9];
    const float* qb1 = (const float*)d_in[10];
    const float* qW2 = (const float*)d_in[11];
    const float* qb2 = (const float*)d_in[12];
    const float* qW3 = (const float*)d_in[13];
    const float* qb3 = (const float*)d_in[14];
    float* out = (float*)d_out;
    float* ws  = (float*)d_ws;

    hipMemsetAsync(d_ws, 0, 64, stream);   // zero loss accumulators + block counter
    fused_kernel<<<NBLK, NT, 0, stream>>>(dw, X0, R0, pW1, pb1, pW2, pb2, pW3, pb3,
                                          qW1, qb1, qW2, qb2, qW3, qb3, ws, out);
}

// Round 7
// 197.730 us; speedup vs baseline: 1.2094x; 1.2094x over previous
//
#include <hip/hip_runtime.h>
#include <hip/hip_bf16.h>
#include <math.h>

#define NSTEP 100
#define BATCH 16384
#define MB 16            // samples per block == MFMA dim 16
#define NBLK (BATCH/MB)  // 1024 blocks x 4 waves = 4096 waves -> 4/SIMD
#define NT 256

#define C_ALPHA 0.05f
#define C_SIGMA 0.2f
#define C_THETA 0.3f
#define C_DT    0.01f
#define C_LOWER 1e-6f
#define C_PEN   100.0f
#define LOG2E   1.4426950408889634f
#define TSCALE  (2.0f * LOG2E)      // tanh(z) = 1 - 2/(exp2(TSCALE*z)+1) (init/p-net only)
#define CRT ( 0.015f * C_DT * LOG2E)
#define CRW ( 0.1f * LOG2E)
#define CPT (-0.095f * C_DT * LOG2E)
#define CPW (-0.3f * LOG2E)

// PWL tanh table coordinate: u = TSC*z + TOFF, 1024 segments over z in [-8, 8]
#define TSC   64.0f
#define TOFF  512.0f
#define TMAX  1023.999f
#define AXD   (1.0f + C_ALPHA * C_DT)
#define SIGTHDT (C_SIGMA * C_THETA * C_DT)

// Cross-wave LDS sync WITHOUT the vmcnt(0) drain __syncthreads() implies.
#define WG_BARRIER() asm volatile("s_waitcnt lgkmcnt(0)\n\ts_barrier" ::: "memory")

typedef __attribute__((ext_vector_type(8))) short bf16x8;
typedef __attribute__((ext_vector_type(4))) float f32x4;
typedef __attribute__((ext_vector_type(4), aligned(4))) float f32x4a;

__device__ __forceinline__ float tanh_pre(float zs) {  // init/p-net only (trans)
    float e = __builtin_amdgcn_exp2f(zs);
    return 1.0f - 2.0f * __builtin_amdgcn_rcpf(e + 1.0f);
}
__device__ __forceinline__ unsigned f2bf_u(float f) {  // RNE
    unsigned u = __float_as_uint(f);
    return (u + 0x7FFFu + ((u >> 16) & 1u)) >> 16;
}
__device__ __forceinline__ unsigned pack_bf16(float a, float b) {
    union { __hip_bfloat162 h; unsigned u; } cv;
    cv.h = __float22bfloat162_rn(make_float2(a, b));   // v_cvt_pk_bf16_f32
    return cv.u;
}
// sum across each 16-lane row via DPP row_ror butterfly (epilogue loss only)
__device__ __forceinline__ float dpp_row_sum16(float v) {
    int t;
    t = __builtin_amdgcn_update_dpp(0, __float_as_int(v), 0x128, 0xF, 0xF, true);
    v += __int_as_float(t);
    t = __builtin_amdgcn_update_dpp(0, __float_as_int(v), 0x124, 0xF, 0xF, true);
    v += __int_as_float(t);
    t = __builtin_amdgcn_update_dpp(0, __float_as_int(v), 0x122, 0xF, 0xF, true);
    v += __int_as_float(t);
    t = __builtin_amdgcn_update_dpp(0, __float_as_int(v), 0x121, 0xF, 0xF, true);
    v += __int_as_float(t);
    return v;
}

__global__ __launch_bounds__(NT, 4) void fused_kernel(
        const float* __restrict__ dw, const float* __restrict__ X0,
        const float* __restrict__ R0,
        const float* __restrict__ pW1, const float* __restrict__ pb1,
        const float* __restrict__ pW2, const float* __restrict__ pb2,
        const float* __restrict__ pW3, const float* __restrict__ pb3,
        const float* __restrict__ qW1, const float* __restrict__ qb1,
        const float* __restrict__ qW2, const float* __restrict__ qb2,
        const float* __restrict__ qW3, const float* __restrict__ qb3,
        float* __restrict__ ws, float* __restrict__ out) {
    __shared__ __align__(16) unsigned short sW2T[64 * 72];  // bf16 W2^T [n][k] * TSC
    __shared__ __align__(16) float sdw[MB * NSTEP];
    __shared__ __align__(16) float2 sTab[1024];             // PWL tanh: {t, dt}
    __shared__ __align__(16) uint2 sA2[2][2][64][2];  // [parity][kstep][lane][half]
    __shared__ __align__(16) float sP[2][4][16];      // [parity][wave][sample]

    const int tid = threadIdx.x;
    const int lane = tid & 63;
    const int wv = tid >> 6;               // wave role: n-tile owner + k-chunk owner
    const int ks_own = wv >> 1;            // which kstep fragment this wave feeds
    const int half = wv & 1;               // which 8-byte half of that fragment
    const int b0 = blockIdx.x * MB;
    const int l15 = lane & 15, quad = lane >> 4;

    // ---- stage dw (coalesced float4), W2^T (bf16 * TSC), tanh PWL table ----
    {
        const float4* g = (const float4*)(dw + (size_t)b0 * NSTEP);
        float4* s = (float4*)sdw;
        for (int u = tid; u < MB * NSTEP / 4; u += NT) s[u] = g[u];
    }
    for (int u4 = tid; u4 < 1024; u4 += NT) {
        float4 w = ((const float4*)qW2)[u4];
        int base = u4 * 4;
        int k = base >> 6, n = base & 63;      // qW2[k*64+n] = W2[k][n]
        sW2T[(n + 0) * 72 + k] = (unsigned short)f2bf_u(w.x * TSC);
        sW2T[(n + 1) * 72 + k] = (unsigned short)f2bf_u(w.y * TSC);
        sW2T[(n + 2) * 72 + k] = (unsigned short)f2bf_u(w.z * TSC);
        sW2T[(n + 3) * 72 + k] = (unsigned short)f2bf_u(w.w * TSC);
    }
    for (int u = tid; u < 1024; u += NT) {     // build PWL table (one-time trans)
        float z0 = (float)u * (1.0f / TSC) - 8.0f;
        float t0 = tanh_pre(TSCALE * z0);
        float t1 = tanh_pre(TSCALE * (z0 + 1.0f / TSC));
        sTab[u] = make_float2(t0, t1 - t0);
    }
    __syncthreads();

    // PWL tanh eval: u is already the table coordinate (weights pre-scaled)
    auto tab = [&](float u) -> float {
        float uc = __builtin_amdgcn_fmed3f(u, 0.0f, TMAX);
        int idx = (int)uc;                     // trunc == floor (uc >= 0)
        float f = uc - (float)idx;
        float2 e = sTab[idx];
        return fmaf(f, e.y, e.x);
    };

    // resident W2^T fragments: this wave's n-tile (nt = wv), 2 k-steps.
    // Used as MFMA *A* operand: lane l15 = row = n-within-tile, quad = k-chunk.
    bf16x8 Bw0, Bw1;
    {
        const unsigned short* rp = &sW2T[(wv * 16 + l15) * 72 + quad * 8];
        Bw0 = *(const bf16x8*)rp;
        Bw1 = *(const bf16x8*)(rp + 32);
    }
    // layer-1 consts (pre-scaled by TSC, +TOFF in bias): this wave's 4 k's
    float tco[4], w1xs[4], w1rs[4], b1s[4];
    {
        const int kb = ks_own * 32 + quad * 8 + half * 4;
        #pragma unroll
        for (int j = 0; j < 4; j++) {
            tco[j]  = qW1[kb + j] * (2.0f * C_DT * TSC);
            w1xs[j] = qW1[64 + kb + j] * TSC;
            w1rs[j] = qW1[128 + kb + j] * TSC;
            b1s[j]  = qb1[kb + j] * TSC + TOFF;
        }
    }
    // swapped-output consts: acc[r] = table-coord of h2pre[n = wv*16+quad*4+r][sample l15]
    f32x4 b2w;
    float w3w[4];
    #pragma unroll
    for (int r = 0; r < 4; r++) {
        b2w[r] = qb2[wv * 16 + quad * 4 + r] * TSC + TOFF;
        w3w[r] = qW3[wv * 16 + quad * 4 + r];
    }
    const float b3 = qb3[0];
    const float X0v = X0[0], R0s = R0[0];

    // ---- p-net: p0, dp0 (one-time; trans ok) ----
    float p0, dp0;
    {
        float pre = fmaf(pW1[64 + lane], X0v, fmaf(pW1[128 + lane], R0s, pb1[lane]));
        float h1 = tanh_pre(TSCALE * pre);
        float d1 = (1.0f - h1 * h1) * pW1[64 + lane];
        float a0 = pb2[lane], a1 = 0.f, a2 = 0.f, a3 = 0.f;
        float e0 = 0.f, e1 = 0.f, e2 = 0.f, e3 = 0.f;
        for (int i2 = 0; i2 < 64; i2 += 4) {
            float w0 = pW2[(i2 + 0) * 64 + lane];
            float w1 = pW2[(i2 + 1) * 64 + lane];
            float w2 = pW2[(i2 + 2) * 64 + lane];
            float w3 = pW2[(i2 + 3) * 64 + lane];
            a0 = fmaf(__shfl(h1, i2 + 0), w0, a0); e0 = fmaf(__shfl(d1, i2 + 0), w0, e0);
            a1 = fmaf(__shfl(h1, i2 + 1), w1, a1); e1 = fmaf(__shfl(d1, i2 + 1), w1, e1);
            a2 = fmaf(__shfl(h1, i2 + 2), w2, a2); e2 = fmaf(__shfl(d1, i2 + 2), w2, e2);
            a3 = fmaf(__shfl(h1, i2 + 3), w3, a3); e3 = fmaf(__shfl(d1, i2 + 3), w3, e3);
        }
        float pre2 = (a0 + a1) + (a2 + a3);
        float dpre2 = (e0 + e1) + (e2 + e3);
        float h2 = tanh_pre(TSCALE * pre2);
        float d2 = (1.0f - h2 * h2) * dpre2;
        float c1 = h2 * pW3[lane], c2 = d2 * pW3[lane];
        #pragma unroll
        for (int o = 1; o < 64; o <<= 1) {
            c1 += __shfl_xor(c1, o);
            c2 += __shfl_xor(c2, o);
        }
        p0 = c1 + pb3[0]; dp0 = c2;
    }
    const float mdp0 = -dp0;

    // ---- cooperative q-net: 4 waves, table tanh, swapped-operand reduce ----
    auto qnet = [&](int par, float fi, float xv, float rv) -> float {
        union { uint2 u2; unsigned u[2]; } Aloc;
        {
            float z0 = fmaf(w1rs[0], rv, fmaf(w1xs[0], xv, fmaf(tco[0], fi, b1s[0])));
            float z1 = fmaf(w1rs[1], rv, fmaf(w1xs[1], xv, fmaf(tco[1], fi, b1s[1])));
            float z2 = fmaf(w1rs[2], rv, fmaf(w1xs[2], xv, fmaf(tco[2], fi, b1s[2])));
            float z3 = fmaf(w1rs[3], rv, fmaf(w1xs[3], xv, fmaf(tco[3], fi, b1s[3])));
            Aloc.u[0] = pack_bf16(tab(z0), tab(z1));
            Aloc.u[1] = pack_bf16(tab(z2), tab(z3));
        }
        sA2[par][ks_own][lane][half] = Aloc.u2;
        WG_BARRIER();                          // B1: all A half-fragments in LDS
        bf16x8 A0 = *(const bf16x8*)&sA2[par][0][lane][0];   // conflict-free b128
        bf16x8 A1 = *(const bf16x8*)&sA2[par][1][lane][0];
        // swapped operands: D[row = n-within-tile][col = SAMPLE = lane&15]
        f32x4 acc = b2w;
        acc = __builtin_amdgcn_mfma_f32_16x16x32_bf16(Bw0, A0, acc, 0, 0, 0);
        acc = __builtin_amdgcn_mfma_f32_16x16x32_bf16(Bw1, A1, acc, 0, 0, 0);
        float ps = fmaf(tab(acc[0]), w3w[0],
                   fmaf(tab(acc[1]), w3w[1],
                   fmaf(tab(acc[2]), w3w[2], tab(acc[3]) * w3w[3])));
        ps += __shfl_xor(ps, 16);              // sum quads: full 16-n partial
        ps += __shfl_xor(ps, 32);              // replicated on all lanes
        if (quad == 0) sP[par][wv][l15] = ps;  // 16 lanes, banks 0..15
        WG_BARRIER();                          // B2: partials exchanged
        return ((sP[par][0][l15] + sP[par][1][l15]) +
                (sP[par][2][l15] + sP[par][3][l15])) + b3;
    };

    // ---- t=0 row + initial pi ----
    float x = X0v, minx = X0v;
    float R = R0s, pm = p0;                    // multiplicative carries
    float pi = qnet(0, 0.0f, X0v, R0s);
    if (wv == 3) {
        size_t base = (size_t)(b0 + l15) * 5;
        if (quad == 0) {
            f32x4a o = {X0v, R0s, pi, -p0};
            *(f32x4a*)(out + base) = o;
        } else if (quad == 1) {
            out[base + 4] = mdp0;
        }
    }

    float dw_next = sdw[l15 * NSTEP];
    #pragma unroll 1
    for (int i = 0; i < NSTEP - 1; i++) {
        const float fi = (float)(i + 1);
        float dwv = dw_next;
        dw_next = sdw[l15 * NSTEP + i + 1];
        R  *= __builtin_amdgcn_exp2f(fmaf(CRW, dwv, CRT));
        pm *= __builtin_amdgcn_exp2f(fmaf(CPW, dwv, CPT));
        float sp = fmaf(dwv, C_SIGMA, SIGTHDT);
        x = fmaf(x, AXD, pi * sp);
        minx = fminf(minx, x);
        float pin = qnet((i + 1) & 1, fi, x, R);
        if (wv == 3) {
            size_t base = ((size_t)(i + 1) * BATCH + b0 + l15) * 5;
            if (quad == 0) {
                f32x4a o = {x, R, pin, -pm};
                *(f32x4a*)(out + base) = o;
            } else if (quad == 1) {
                out[base + 4] = mdp0;
            }
        }
        pi = pin;
    }

    // ---- final step (pi not updated) + losses ----
    {
        float dwv = dw_next;
        R  *= __builtin_amdgcn_exp2f(fmaf(CRW, dwv, CRT));
        pm *= __builtin_amdgcn_exp2f(fmaf(CPW, dwv, CPT));
        float sp = fmaf(dwv, C_SIGMA, SIGTHDT);
        x = fmaf(x, AXD, pi * sp);
        minx = fminf(minx, x);
        float Rf = R, pf = pm;
        if (wv == 3) {
            size_t base = ((size_t)NSTEP * BATCH + b0 + l15) * 5;
            if (quad == 0) {
                f32x4a o = {x, Rf, pi, -pf};
                *(f32x4a*)(out + base) = o;
            } else if (quad == 1) {
                out[base + 4] = mdp0;
            }
        }
        if (wv == 0) {
            float xc = fmaxf(x, C_LOWER);
            float ux = Rf * rsqrtf(xc);           // R * xc^(gamma-1), gamma=0.5
            float uval = 2.0f * Rf * sqrtf(xc);   // R * xc^gamma / gamma
            float d = fmaxf(C_LOWER - minx, 0.0f);
            float pen = C_PEN * d * d;
            float t1 = pf + ux;
            float v1 = dpp_row_sum16(t1 * t1 + pen);
            float v2 = dpp_row_sum16(-uval + pen);
            if (lane == 0) {
                atomicAdd(&ws[3], v1);
                atomicAdd(&ws[4], v2);
                __threadfence();
                int old = atomicAdd((int*)(ws + 5), 1);
                if (old == NBLK - 1) {   // last block finalizes losses
                    float lp = atomicAdd(&ws[3], 0.0f) * (1.0f / (float)BATCH);
                    float lq = atomicAdd(&ws[4], 0.0f) * (1.0f / (float)BATCH);
                    out[(size_t)(NSTEP + 1) * BATCH * 5] = lp;
                    out[(size_t)(NSTEP + 1) * BATCH * 5 + 1] = lp + lq;
                }
            }
        }
    }
}

extern "C" void kernel_launch(void* const* d_in, const int* in_sizes, int n_in,
                              void* d_out, int out_size, void* d_ws, size_t ws_size,
                              hipStream_t stream) {
    const float* dw  = (const float*)d_in[0];
    const float* X0  = (const float*)d_in[1];
    const float* R0  = (const float*)d_in[2];
    const float* pW1 = (const float*)d_in[3];
    const float* pb1 = (const float*)d_in[4];
    const float* pW2 = (const float*)d_in[5];
    const float* pb2 = (const float*)d_in[6];
    const float* pW3 = (const float*)d_in[7];
    const float* pb3 = (const float*)d_in[8];
    const float* qW1 = (const float*)d_in[9];
    const float* qb1 = (const float*)d_in[10];
    const float* qW2 = (const float*)d_in[11];
    const float* qb2 = (const float*)d_in[12];
    const float* qW3 = (const float*)d_in[13];
    const float* qb3 = (const float*)d_in[14];
    float* out = (float*)d_out;
    float* ws  = (float*)d_ws;

    hipMemsetAsync(d_ws, 0, 64, stream);   // zero loss accumulators + block counter
    fused_kernel<<<NBLK, NT, 0, stream>>>(dw, X0, R0, pW1, pb1, pW2, pb2, pW3, pb3,
                                          qW1, qb1, qW2, qb2, qW3, qb3, ws, out);
}